// Round 1
// baseline (162.787 us; speedup 1.0000x reference)
//
#include <hip/hip_runtime.h>

#define BI 128
#define BH 256
#define MT 32
#define NT 256

using f32x4  = __attribute__((ext_vector_type(4))) float;
using short8 = __attribute__((ext_vector_type(8))) short;

// ---------- bf16 helpers (RNE) ----------
__device__ __forceinline__ unsigned short f2bf(float f) {
  unsigned u = __float_as_uint(f);
  u = (u + 0x7FFFu + ((u >> 16) & 1u)) >> 16;
  return (unsigned short)u;
}
__device__ __forceinline__ float bf2f(unsigned short h) {
  return __uint_as_float(((unsigned)h) << 16);
}
__device__ __forceinline__ float fast_tanh(float v) {
  return 1.f - 2.f / (1.f + __expf(2.f * v));
}
__device__ __forceinline__ float fast_sigmoid(float v) {
  return 1.f / (1.f + __expf(-v));
}

// ---------- weight packing: W (HxK row-major f32) -> hi/lo bf16 in B-fragment order ----------
// fragment (nf, kt): lane l supplies W[nf*16 + (l&15)][kt*32 + (l>>4)*8 + j], j=0..7
__global__ void pack_w(const float* __restrict__ W, unsigned short* __restrict__ hi,
                       unsigned short* __restrict__ lo, int K, int total) {
  int t = blockIdx.x * blockDim.x + threadIdx.x;
  if (t >= total) return;
  int lane = t & 63;
  int tile = t >> 6;
  int KT = K >> 5;
  int nf = tile / KT, kt = tile - nf * KT;
  int n  = nf * 16 + (lane & 15);
  int k0 = kt * 32 + (lane >> 4) * 8;
  const float* src = W + (size_t)n * K + k0;
#pragma unroll
  for (int j = 0; j < 8; ++j) {
    float v = src[j];
    unsigned short h = f2bf(v);
    hi[(size_t)t * 8 + j] = h;
    lo[(size_t)t * 8 + j] = f2bf(v - bf2f(h));
  }
}

// ---------- stage 4 floats as hi/lo bf16 into swizzled LDS ----------
__device__ __forceinline__ void stash4(char* hiB, char* loB, int row, int c4, int rowStride, f32x4 v) {
  unsigned short h0 = f2bf(v[0]), h1 = f2bf(v[1]), h2 = f2bf(v[2]), h3 = f2bf(v[3]);
  unsigned short l0 = f2bf(v[0] - bf2f(h0)), l1 = f2bf(v[1] - bf2f(h1));
  unsigned short l2 = f2bf(v[2] - bf2f(h2)), l3 = f2bf(v[3] - bf2f(h3));
  unsigned h01 = (unsigned)h0 | ((unsigned)h1 << 16);
  unsigned h23 = (unsigned)h2 | ((unsigned)h3 << 16);
  unsigned l01 = (unsigned)l0 | ((unsigned)l1 << 16);
  unsigned l23 = (unsigned)l2 | ((unsigned)l3 << 16);
  int off = row * rowStride + ((c4 * 2) ^ ((row & 7) << 4));
  *(unsigned long long*)(hiB + off) =
      (unsigned long long)h01 | ((unsigned long long)h23 << 32);
  *(unsigned long long*)(loB + off) =
      (unsigned long long)l01 | ((unsigned long long)l23 << 32);
}

// ---------- split-bf16 GEMM tile: acc += Atile(32 x 32*KT) @ W^T, per-wave 32x64 ----------
template <int KT>
__device__ __forceinline__ void mm_tile(const char* __restrict__ smem,
                                        int aHiOff, int aLoOff, int rowStride,
                                        const unsigned short* __restrict__ bHiP,
                                        const unsigned short* __restrict__ bLoP,
                                        int wid, int lane, f32x4 (&acc)[2][4]) {
  const int lrow = lane & 15;
  const int lk = lane >> 4;
  const short8* bHi = (const short8*)bHiP;
  const short8* bLo = (const short8*)bLoP;
#pragma unroll
  for (int kt = 0; kt < KT; ++kt) {
    short8 ah[2], al[2];
#pragma unroll
    for (int mf = 0; mf < 2; ++mf) {
      int row = mf * 16 + lrow;
      int off = row * rowStride + ((kt * 64 + lk * 16) ^ ((row & 7) << 4));
      ah[mf] = *(const short8*)(smem + aHiOff + off);
      al[mf] = *(const short8*)(smem + aLoOff + off);
    }
#pragma unroll
    for (int nf = 0; nf < 4; ++nf) {
      int bi = ((wid * 4 + nf) * KT + kt) * 64 + lane;
      short8 bh = bHi[bi];
      short8 bl = bLo[bi];
#pragma unroll
      for (int mf = 0; mf < 2; ++mf) {
        acc[mf][nf] = __builtin_amdgcn_mfma_f32_16x16x32_bf16(ah[mf], bh, acc[mf][nf], 0, 0, 0);
        acc[mf][nf] = __builtin_amdgcn_mfma_f32_16x16x32_bf16(ah[mf], bl, acc[mf][nf], 0, 0, 0);
        acc[mf][nf] = __builtin_amdgcn_mfma_f32_16x16x32_bf16(al[mf], bh, acc[mf][nf], 0, 0, 0);
      }
    }
  }
}

// LDS layout (bytes), total 81920 (2 blocks/CU):
//     0 : h_hi  [32][256] bf16 swizzled   16384
// 16384 : h_lo                            16384
// 32768 : ha_hi                           16384
// 49152 : ha_lo                           16384
// 65536 : x_hi  [32][128] bf16 swizzled    8192   (reused for ew[32] after GEMM1)
// 73728 : x_lo                             8192
__global__ __launch_bounds__(NT, 2) void liquid_kernel(
    const float* __restrict__ x, const float* __restrict__ prev,
    const float* __restrict__ hidden,
    const float* __restrict__ w_in_b, const float* __restrict__ w_rec_b,
    const float* __restrict__ attn_b,
    const float* __restrict__ ev_w, const float* __restrict__ ev_b,
    const float* __restrict__ tau,
    const unsigned short* __restrict__ win_hi, const unsigned short* __restrict__ win_lo,
    const unsigned short* __restrict__ attn_hi, const unsigned short* __restrict__ attn_lo,
    const unsigned short* __restrict__ wrec_hi, const unsigned short* __restrict__ wrec_lo,
    float* __restrict__ out, int Bn) {
  extern __shared__ char smem[];
  const int tid = threadIdx.x;
  const int lane = tid & 63;
  const int wid = tid >> 6;
  const int r0 = blockIdx.x * MT;

  // ---- stage hidden (32x256) as hi/lo bf16 ----
#pragma unroll
  for (int it = 0; it < 8; ++it) {
    int idx4 = it * NT + tid;
    int row = idx4 >> 6;
    int c4 = (idx4 & 63) << 2;
    f32x4 v = *(const f32x4*)(hidden + (size_t)(r0 + row) * BH + c4);
    stash4(smem, smem + 16384, row, c4, 512, v);
  }
  // ---- stage x (32x128) ----
#pragma unroll
  for (int it = 0; it < 4; ++it) {
    int idx4 = it * NT + tid;
    int row = idx4 >> 5;
    int c4 = (idx4 & 31) << 2;
    f32x4 v = *(const f32x4*)(x + (size_t)(r0 + row) * BI + c4);
    stash4(smem + 65536, smem + 73728, row, c4, 256, v);
  }
  // ---- event weight: 8 threads per row, f32 dot of 256 ----
  float my_ew = 0.f;
  {
    int r = tid >> 3, p = tid & 7;
    float s = 0.f;
    if (p < 4) {
      const float* xr = x + (size_t)(r0 + r) * BI + p * 32;
      const float* wr = ev_w + p * 32;
#pragma unroll
      for (int i = 0; i < 8; ++i) {
        f32x4 a = *(const f32x4*)(xr + i * 4);
        f32x4 w = *(const f32x4*)(wr + i * 4);
        s += a[0] * w[0] + a[1] * w[1] + a[2] * w[2] + a[3] * w[3];
      }
    } else {
      const float* pr = prev + (size_t)(r0 + r) * BI + (p - 4) * 32;
      const float* wr = ev_w + 128 + (p - 4) * 32;
#pragma unroll
      for (int i = 0; i < 8; ++i) {
        f32x4 a = *(const f32x4*)(pr + i * 4);
        f32x4 w = *(const f32x4*)(wr + i * 4);
        s += a[0] * w[0] + a[1] * w[1] + a[2] * w[2] + a[3] * w[3];
      }
    }
    s += __shfl_xor(s, 1);
    s += __shfl_xor(s, 2);
    s += __shfl_xor(s, 4);
    if (p == 0) {
      my_ew = fast_sigmoid(s + ev_b[0]);
      out[(size_t)Bn * BH + r0 + r] = my_ew;
    }
  }
  __syncthreads();

  const int lrow = lane & 15;
  const int lk = lane >> 4;

  // ---- GEMM2: attn preact = hidden @ attn_w^T ----
  f32x4 acc[2][4] = {};
  mm_tile<8>(smem, 0, 16384, 512, attn_hi, attn_lo, wid, lane, acc);

  // aw = sigmoid(+b); ha = hidden * aw -> LDS hi/lo
#pragma unroll
  for (int nf = 0; nf < 4; ++nf) {
    int col = wid * 64 + nf * 16 + lrow;
    float bb = attn_b[col];
#pragma unroll
    for (int mf = 0; mf < 2; ++mf) {
#pragma unroll
      for (int j = 0; j < 4; ++j) {
        int row = mf * 16 + lk * 4 + j;
        float aw = fast_sigmoid(acc[mf][nf][j] + bb);
        int hoff = row * 512 + ((col * 2) ^ ((row & 7) << 4));
        float h = bf2f(*(const unsigned short*)(smem + hoff)) +
                  bf2f(*(const unsigned short*)(smem + 16384 + hoff));
        float hav = h * aw;
        unsigned short hh = f2bf(hav);
        *(unsigned short*)(smem + 32768 + hoff) = hh;
        *(unsigned short*)(smem + 49152 + hoff) = f2bf(hav - bf2f(hh));
      }
    }
  }
  __syncthreads();

  // ---- GEMM1: ic = tanh(x @ W_in^T + b) (kept in regs) ----
  f32x4 ic[2][4] = {};
  mm_tile<4>(smem, 65536, 73728, 256, win_hi, win_lo, wid, lane, ic);
#pragma unroll
  for (int nf = 0; nf < 4; ++nf) {
    float bb = w_in_b[wid * 64 + nf * 16 + lrow];
#pragma unroll
    for (int mf = 0; mf < 2; ++mf)
#pragma unroll
      for (int j = 0; j < 4; ++j)
        ic[mf][nf][j] = fast_tanh(ic[mf][nf][j] + bb);
  }

  // x tile dead -> park ew[32] there
  __syncthreads();
  if ((tid & 7) == 0) *(float*)(smem + 65536 + (tid >> 3) * 4) = my_ew;
  __syncthreads();

  // ---- GEMM3: rec preact = ha @ W_rec^T ----
  f32x4 rcc[2][4] = {};
  mm_tile<8>(smem, 32768, 49152, 512, wrec_hi, wrec_lo, wid, lane, rcc);

  // ---- epilogue ----
#pragma unroll
  for (int nf = 0; nf < 4; ++nf) {
    int col = wid * 64 + nf * 16 + lrow;
    float brec = w_rec_b[col];
    float t = tau[col];
    t = fminf(fmaxf(t, 0.1f), 10.f);
    float dt_t = 0.1f / t;
#pragma unroll
    for (int mf = 0; mf < 2; ++mf) {
#pragma unroll
      for (int j = 0; j < 4; ++j) {
        int row = mf * 16 + lk * 4 + j;
        float rc = fast_tanh(rcc[mf][nf][j] + brec);
        int hoff = row * 512 + ((col * 2) ^ ((row & 7) << 4));
        float h = bf2f(*(const unsigned short*)(smem + hoff)) +
                  bf2f(*(const unsigned short*)(smem + 16384 + hoff));
        float e = *(const float*)(smem + 65536 + row * 4);
        out[(size_t)(r0 + row) * BH + col] = h + dt_t * (ic[mf][nf][j] + rc - h) * (1.f + e);
      }
    }
  }
}

extern "C" void kernel_launch(void* const* d_in, const int* in_sizes, int n_in,
                              void* d_out, int out_size, void* d_ws, size_t ws_size,
                              hipStream_t stream) {
  const float* x       = (const float*)d_in[0];
  const float* prev    = (const float*)d_in[1];
  const float* hidden  = (const float*)d_in[2];
  const float* W_in_w  = (const float*)d_in[3];
  const float* W_in_b  = (const float*)d_in[4];
  const float* W_rec_w = (const float*)d_in[5];
  const float* W_rec_b = (const float*)d_in[6];
  const float* attn_w  = (const float*)d_in[7];
  const float* attn_b  = (const float*)d_in[8];
  const float* ev_w    = (const float*)d_in[9];
  const float* ev_b    = (const float*)d_in[10];
  const float* tau     = (const float*)d_in[11];
  int Bn = in_sizes[0] / BI;

  unsigned short* ws = (unsigned short*)d_ws;
  unsigned short* win_hi  = ws;            // 32768 elems
  unsigned short* win_lo  = ws + 32768;
  unsigned short* attn_hi = ws + 65536;    // 65536 elems
  unsigned short* attn_lo = ws + 131072;
  unsigned short* wrec_hi = ws + 196608;
  unsigned short* wrec_lo = ws + 262144;   // end: 327680 elems = 640 KiB

  pack_w<<<(4096 + 255) / 256, 256, 0, stream>>>(W_in_w, win_hi, win_lo, BI, 4096);
  pack_w<<<(8192 + 255) / 256, 256, 0, stream>>>(attn_w, attn_hi, attn_lo, BH, 8192);
  pack_w<<<(8192 + 255) / 256, 256, 0, stream>>>(W_rec_w, wrec_hi, wrec_lo, BH, 8192);

  liquid_kernel<<<Bn / MT, NT, 81920, stream>>>(
      x, prev, hidden, W_in_b, W_rec_b, attn_b, ev_w, ev_b, tau,
      win_hi, win_lo, attn_hi, attn_lo, wrec_hi, wrec_lo,
      (float*)d_out, Bn);
}

// Round 2
// 134.145 us; speedup vs baseline: 1.2135x; 1.2135x over previous
//
#include <hip/hip_runtime.h>

#define BI 128
#define BH 256
#define MT 32
#define NT 256

using f32x4  = __attribute__((ext_vector_type(4))) float;
using short8 = __attribute__((ext_vector_type(8))) short;

// ---------- bf16 helpers (RNE) ----------
__device__ __forceinline__ unsigned short f2bf(float f) {
  unsigned u = __float_as_uint(f);
  u = (u + 0x7FFFu + ((u >> 16) & 1u)) >> 16;
  return (unsigned short)u;
}
__device__ __forceinline__ float bf2f(unsigned short h) {
  return __uint_as_float(((unsigned)h) << 16);
}
__device__ __forceinline__ float fast_tanh(float v) {
  return 1.f - 2.f / (1.f + __expf(2.f * v));
}
__device__ __forceinline__ float fast_sigmoid(float v) {
  return 1.f / (1.f + __expf(-v));
}

// ---------- weight packing: W (HxK row-major f32) -> bf16 in B-fragment order ----------
// fragment (nf, kt): lane l supplies W[nf*16 + (l&15)][kt*32 + (l>>4)*8 + j], j=0..7
__global__ void pack_w(const float* __restrict__ W, unsigned short* __restrict__ dst,
                       int K, int total) {
  int t = blockIdx.x * blockDim.x + threadIdx.x;
  if (t >= total) return;
  int lane = t & 63;
  int tile = t >> 6;
  int KT = K >> 5;
  int nf = tile / KT, kt = tile - nf * KT;
  int n  = nf * 16 + (lane & 15);
  int k0 = kt * 32 + (lane >> 4) * 8;
  const float* src = W + (size_t)n * K + k0;
#pragma unroll
  for (int j = 0; j < 8; ++j) dst[(size_t)t * 8 + j] = f2bf(src[j]);
}

// LDS layout (bytes), total 32896 -> 4 blocks/CU:
//     0 : h_bf  [32][256] bf16, XOR-swizzled rows (16384)
// 16384 : ha_bf [32][256] bf16, XOR-swizzled rows (16384)
// 32768 : ew[32] f32 (128)
__global__ __launch_bounds__(NT, 4) void liquid_kernel(
    const float* __restrict__ x, const float* __restrict__ prev,
    const float* __restrict__ hidden,
    const float* __restrict__ w_in_b, const float* __restrict__ w_rec_b,
    const float* __restrict__ attn_b,
    const float* __restrict__ ev_w, const float* __restrict__ ev_b,
    const float* __restrict__ tau,
    const unsigned short* __restrict__ win_p, const unsigned short* __restrict__ attn_p,
    const unsigned short* __restrict__ wrec_p,
    float* __restrict__ out, int Bn) {
  extern __shared__ char smem[];
  const int tid = threadIdx.x;
  const int lane = tid & 63;
  const int wid = tid >> 6;
  const int r0 = blockIdx.x * MT;

  // ---- stage hidden (32x256) as bf16, swizzled ----
#pragma unroll
  for (int it = 0; it < 8; ++it) {
    int idx4 = it * NT + tid;
    int row = idx4 >> 6;
    int c8 = (idx4 & 63) * 8;  // byte offset of 4 bf16
    f32x4 v = *(const f32x4*)(hidden + (size_t)(r0 + row) * BH + (idx4 & 63) * 4);
    unsigned h01 = (unsigned)f2bf(v[0]) | ((unsigned)f2bf(v[1]) << 16);
    unsigned h23 = (unsigned)f2bf(v[2]) | ((unsigned)f2bf(v[3]) << 16);
    *(unsigned long long*)(smem + row * 512 + (c8 ^ ((row & 7) << 4))) =
        (unsigned long long)h01 | ((unsigned long long)h23 << 32);
  }

  // ---- event weight: 8 threads per row, f32 dot of 256 ----
  {
    int r = tid >> 3, p = tid & 7;
    float s = 0.f;
    const float* src = (p < 4) ? (x + (size_t)(r0 + r) * BI + p * 32)
                               : (prev + (size_t)(r0 + r) * BI + (p - 4) * 32);
    const float* wr = ev_w + p * 32;
#pragma unroll
    for (int i = 0; i < 8; ++i) {
      f32x4 a = *(const f32x4*)(src + i * 4);
      f32x4 w = *(const f32x4*)(wr + i * 4);
      s += a[0] * w[0] + a[1] * w[1] + a[2] * w[2] + a[3] * w[3];
    }
    s += __shfl_xor(s, 1);
    s += __shfl_xor(s, 2);
    s += __shfl_xor(s, 4);
    if (p == 0) {
      float ew = fast_sigmoid(s + ev_b[0]);
      *(float*)(smem + 32768 + r * 4) = ew;
      out[(size_t)Bn * BH + r0 + r] = ew;
    }
  }
  __syncthreads();

  const int lrow = lane & 15;
  const int lk = lane >> 4;

  // ---- GEMM2: attn preact = hidden @ attn_w^T (A from LDS, B from L2) ----
  f32x4 acc[2][4] = {};
  {
    const short8* bW = (const short8*)attn_p;
#pragma unroll
    for (int kt = 0; kt < 8; ++kt) {
      short8 ah[2];
#pragma unroll
      for (int mf = 0; mf < 2; ++mf) {
        int row = mf * 16 + lrow;
        ah[mf] = *(const short8*)(smem + row * 512 + ((kt * 64 + lk * 16) ^ ((row & 7) << 4)));
      }
#pragma unroll
      for (int nf = 0; nf < 4; ++nf) {
        short8 b = bW[((wid * 4 + nf) * 8 + kt) * 64 + lane];
#pragma unroll
        for (int mf = 0; mf < 2; ++mf)
          acc[mf][nf] = __builtin_amdgcn_mfma_f32_16x16x32_bf16(ah[mf], b, acc[mf][nf], 0, 0, 0);
      }
    }
  }

  // ---- aw = sigmoid(+b); ha = h * aw -> LDS bf16 ----
#pragma unroll
  for (int nf = 0; nf < 4; ++nf) {
    int col = wid * 64 + nf * 16 + lrow;
    float bb = attn_b[col];
#pragma unroll
    for (int mf = 0; mf < 2; ++mf) {
#pragma unroll
      for (int j = 0; j < 4; ++j) {
        int row = mf * 16 + lk * 4 + j;
        float aw = fast_sigmoid(acc[mf][nf][j] + bb);
        int hoff = row * 512 + ((col * 2) ^ ((row & 7) << 4));
        float h = bf2f(*(const unsigned short*)(smem + hoff));
        *(unsigned short*)(smem + 16384 + hoff) = f2bf(h * aw);
      }
    }
  }

  // ---- GEMM1: ic = tanh(x @ W_in^T + b) (A straight from global, L1-warm) ----
  f32x4 ic[2][4] = {};
  {
    const short8* bW = (const short8*)win_p;
#pragma unroll
    for (int kt = 0; kt < 4; ++kt) {
      short8 ax[2];
#pragma unroll
      for (int mf = 0; mf < 2; ++mf) {
        const float* xr = x + (size_t)(r0 + mf * 16 + lrow) * BI + kt * 32 + lk * 8;
        f32x4 a0 = *(const f32x4*)xr;
        f32x4 a1 = *(const f32x4*)(xr + 4);
        short8 t;
        t[0] = (short)f2bf(a0[0]); t[1] = (short)f2bf(a0[1]);
        t[2] = (short)f2bf(a0[2]); t[3] = (short)f2bf(a0[3]);
        t[4] = (short)f2bf(a1[0]); t[5] = (short)f2bf(a1[1]);
        t[6] = (short)f2bf(a1[2]); t[7] = (short)f2bf(a1[3]);
        ax[mf] = t;
      }
#pragma unroll
      for (int nf = 0; nf < 4; ++nf) {
        short8 b = bW[((wid * 4 + nf) * 4 + kt) * 64 + lane];
#pragma unroll
        for (int mf = 0; mf < 2; ++mf)
          ic[mf][nf] = __builtin_amdgcn_mfma_f32_16x16x32_bf16(ax[mf], b, ic[mf][nf], 0, 0, 0);
      }
    }
  }
#pragma unroll
  for (int nf = 0; nf < 4; ++nf) {
    float bb = w_in_b[wid * 64 + nf * 16 + lrow];
#pragma unroll
    for (int mf = 0; mf < 2; ++mf)
#pragma unroll
      for (int j = 0; j < 4; ++j)
        ic[mf][nf][j] = fast_tanh(ic[mf][nf][j] + bb);
  }
  __syncthreads();

  // ---- GEMM3: rec preact = ha @ W_rec^T ----
  f32x4 rcc[2][4] = {};
  {
    const short8* bW = (const short8*)wrec_p;
#pragma unroll
    for (int kt = 0; kt < 8; ++kt) {
      short8 ah[2];
#pragma unroll
      for (int mf = 0; mf < 2; ++mf) {
        int row = mf * 16 + lrow;
        ah[mf] = *(const short8*)(smem + 16384 + row * 512 +
                                  ((kt * 64 + lk * 16) ^ ((row & 7) << 4)));
      }
#pragma unroll
      for (int nf = 0; nf < 4; ++nf) {
        short8 b = bW[((wid * 4 + nf) * 8 + kt) * 64 + lane];
#pragma unroll
        for (int mf = 0; mf < 2; ++mf)
          rcc[mf][nf] = __builtin_amdgcn_mfma_f32_16x16x32_bf16(ah[mf], b, rcc[mf][nf], 0, 0, 0);
      }
    }
  }

  // ---- epilogue: new_h = h + dt/tau * (ic + rc - h) * (1 + ew) ----
  float brec[4], dtt[4];
#pragma unroll
  for (int nf = 0; nf < 4; ++nf) {
    int col = wid * 64 + nf * 16 + lrow;
    brec[nf] = w_rec_b[col];
    float t = tau[col];
    t = fminf(fmaxf(t, 0.1f), 10.f);
    dtt[nf] = 0.1f / t;
  }
#pragma unroll
  for (int mf = 0; mf < 2; ++mf) {
#pragma unroll
    for (int j = 0; j < 4; ++j) {
      int row = mf * 16 + lk * 4 + j;
      float e1 = 1.f + *(const float*)(smem + 32768 + row * 4);
      const float* hrow = hidden + (size_t)(r0 + row) * BH;
      float* orow = out + (size_t)(r0 + row) * BH;
#pragma unroll
      for (int nf = 0; nf < 4; ++nf) {
        int col = wid * 64 + nf * 16 + lrow;
        float rc = fast_tanh(rcc[mf][nf][j] + brec[nf]);
        float h = hrow[col];
        orow[col] = h + dtt[nf] * (ic[mf][nf][j] + rc - h) * e1;
      }
    }
  }
}

extern "C" void kernel_launch(void* const* d_in, const int* in_sizes, int n_in,
                              void* d_out, int out_size, void* d_ws, size_t ws_size,
                              hipStream_t stream) {
  const float* x       = (const float*)d_in[0];
  const float* prev    = (const float*)d_in[1];
  const float* hidden  = (const float*)d_in[2];
  const float* W_in_w  = (const float*)d_in[3];
  const float* W_in_b  = (const float*)d_in[4];
  const float* W_rec_w = (const float*)d_in[5];
  const float* W_rec_b = (const float*)d_in[6];
  const float* attn_w  = (const float*)d_in[7];
  const float* attn_b  = (const float*)d_in[8];
  const float* ev_w    = (const float*)d_in[9];
  const float* ev_b    = (const float*)d_in[10];
  const float* tau     = (const float*)d_in[11];
  int Bn = in_sizes[0] / BI;

  unsigned short* ws = (unsigned short*)d_ws;
  unsigned short* win_p  = ws;             // 32768 elems
  unsigned short* attn_p = ws + 32768;     // 65536 elems
  unsigned short* wrec_p = ws + 98304;     // 65536 elems (end 163840 = 320 KiB)

  pack_w<<<(4096 + 255) / 256, 256, 0, stream>>>(W_in_w, win_p, BI, 4096);
  pack_w<<<(8192 + 255) / 256, 256, 0, stream>>>(attn_w, attn_p, BH, 8192);
  pack_w<<<(8192 + 255) / 256, 256, 0, stream>>>(W_rec_w, wrec_p, BH, 8192);

  liquid_kernel<<<Bn / MT, NT, 32896, stream>>>(
      x, prev, hidden, W_in_b, W_rec_b, attn_b, ev_w, ev_b, tau,
      win_p, attn_p, wrec_p, (float*)d_out, Bn);
}